// Round 12
// baseline (329.280 us; speedup 1.0000x reference)
//
#include <hip/hip_runtime.h>
#include <hip/hip_bf16.h>
#include <math.h>

// ---------------------------------------------------------------------------
// GAT 2-layer forward. CSR aggregation, bf16 gather table, precomputed
// per-edge attention weights in PACKED 8B records {src, bf16w0|bf16w1}.
// bf16 MFMA GEMM (W staged in LDS, XOR-swizzled). CSR build FULLY ATOMIC-FREE
// (global): per-(partition,stripe) LDS histograms -> u16 stripe counts ->
// SINGLE-PASS merged scan (deg-sum + in-place exclusive stripe deltas +
// lookback block prefix) -> LDS-cursor placement (rowptr + u16 delta),
// ONE 8B store per edge. Z denominators FUSED into weight-producing passes
// (fp32, pre-rounding). x2 intermediate stored bf16 (bit-identical to
// converting at gemm2 load). Layer-2 weight refresh is ROW-PARALLEL
// (d == row, wave-resident): lanes cover a row's edges in parallel.
//
//   0) init_ws: W1/W2 -> bf16 copies; zero Z; flags = -1
//   1) gemm_mfma<128,fp32 A>: blocks[0,512) = hist (8 partitions x 64
//      contiguous-range stripes, 25KB LDS, u16 flush); rest = MFMA gemm1.
//   2) scan_full (49 blocks): merged deg-sum + in-place deltas + lookback.
//   3) scatter_z (1024-thr): blocks[0,16)=self-loop z1; blocks[16,528) =
//      atomic-free scatter (lcur = rowptr + u16 delta), packs 8B records,
//      fused z1 (fp32 w) over its edges.
//   4) csr_aggregate -> x2 (bf16 out): 8-deep pipelined gather loop,
//      weights unpacked from record bf16 pair.
//   5) gemm_mfma<64,bf16 A> grid=ntiles (pure gemm2)
//   6) wgt2_z2: row-parallel refresh: lane-parallel over row edges,
//      w = lrexp(si[n]+sj[s]) (fp32 for z2, bf16 pack for storage);
//      self-loop z2 from lane 0. One block_zadd per block.
//   7) csr_aggregate -> out (fp32)
//
// MFMA layout (HW-verified m89): A: lane holds A[l&15][(l>>4)*8+j];
// B: B[(l>>4)*8+j][l&15]; D: row=(l>>4)*4+reg, col=l&15.
// LDS swizzle: W row r, 16B-chunk c at position c ^ (r & CPR-1).
// u16 safety: stripe count <= Eper=12500; per-row delta <= deg(n) < 65536.
// Lookback safety: nb=49 blocks co-resident; publish-before-wait.
// Numerics: record weights bf16 (same rounding class as hq table); z sums
// remain fp32 from unrounded weights.
// ---------------------------------------------------------------------------

#define HP 8             // dst partitions
#define HG 64            // edge stripes
#define NHISTB (HP * HG) // 512 hist/scatter blocks
#define HRANGE_MAX 6272  // compile-time LDS bound for one partition's counters
#define NSELF 16         // self-loop z blocks (1024 threads each)

using short8 = __attribute__((ext_vector_type(8))) short;
using f32x4  = __attribute__((ext_vector_type(4))) float;

__device__ __forceinline__ unsigned f2bf(float x) {  // fp32 -> bf16 (RNE)
  unsigned u = __float_as_uint(x);
  return (u + 0x7fffu + ((u >> 16) & 1u)) >> 16;
}
__device__ __forceinline__ float bflo(unsigned p) { return __uint_as_float(p << 16); }
__device__ __forceinline__ float bfhi(unsigned p) { return __uint_as_float(p & 0xffff0000u); }
__device__ __forceinline__ float lrexp(float a) {   // exp(leaky_relu(a, 0.2))
  a = a >= 0.f ? a : 0.2f * a;
  return __expf(a);
}

// block-wide z reduction (up to 16 waves) + one atomicAdd pair per block
__device__ __forceinline__ void block_zadd(float z0, float z1,
                                           float* __restrict__ Zp) {
  __shared__ float r0[16], r1[16];
  int lane = threadIdx.x & 63, w = threadIdx.x >> 6;
  int nw = blockDim.x >> 6;
#pragma unroll
  for (int off = 32; off; off >>= 1) {
    z0 += __shfl_down(z0, off, 64);
    z1 += __shfl_down(z1, off, 64);
  }
  if (lane == 0) { r0[w] = z0; r1[w] = z1; }
  __syncthreads();
  if (threadIdx.x == 0) {
    float s0 = 0.f, s1 = 0.f;
    for (int i = 0; i < nw; ++i) { s0 += r0[i]; s1 += r1[i]; }
    atomicAdd(&Zp[0], s0);
    atomicAdd(&Zp[1], s1);
  }
}

// W -> bf16 copies + zero Z + lookback flags = -1
__global__ __launch_bounds__(256) void init_ws(
    const float* __restrict__ W1, const float* __restrict__ W2,
    unsigned short* __restrict__ wbf1, unsigned short* __restrict__ wbf2,
    float* __restrict__ Z, int* __restrict__ flags) {
  int tid = blockIdx.x * 256 + threadIdx.x;
  int stride = gridDim.x * 256;
  for (int i = tid; i < 128 * 128; i += stride)
    wbf1[i] = (unsigned short)f2bf(W1[i]);
  for (int i = tid; i < 128 * 64; i += stride)
    wbf2[i] = (unsigned short)f2bf(W2[i]);
  if (tid < 4) Z[tid] = 0.f;
  if (tid < 64) flags[tid] = -1;
}

// MFMA GEMM (h = x @ W^T) + fused attention scores + bf16 pack.
// AB16: A operand is bf16 (x2 intermediate); else fp32 with RNE convert.
// blocks < nhistb run the atomic-free LDS-privatized degree histogram.
template <int FIN, bool AB16>
__global__ __launch_bounds__(256) void gemm_mfma(
    const void* __restrict__ xin, const unsigned short* __restrict__ Wb,
    const float* __restrict__ att, unsigned* __restrict__ hq,
    float* __restrict__ si, float* __restrict__ sj,
    int N,
    const int* __restrict__ dstE, unsigned short* __restrict__ partial,
    int E, int nhistb, int hstep, int eper) {
  const int tid = threadIdx.x;

  constexpr int WB = 128 * FIN * 2;  // bf16 W tile bytes
  constexpr int SMEM = (WB > HRANGE_MAX * 4) ? WB : HRANGE_MAX * 4;
  __shared__ __align__(16) unsigned char smem[SMEM];

  if ((int)blockIdx.x < nhistb) {
    // ---- atomic-free histogram: partition p, stripe g (contiguous) ----
    int* lhist = (int*)smem;
    const int p = blockIdx.x & (HP - 1);
    const int g = blockIdx.x >> 3;        // stripe 0..HG-1
    const int lo = p * hstep;
    for (int i = tid; i < hstep; i += 256) lhist[i] = 0;
    __syncthreads();
    const int eb = g * eper;
    const int ee = min(E, eb + eper);
    int e = eb + tid;
    for (; e + 3 * 256 < ee; e += 4 * 256) {
      int d0 = dstE[e] - lo;
      int d1 = dstE[e + 256] - lo;
      int d2 = dstE[e + 2 * 256] - lo;
      int d3 = dstE[e + 3 * 256] - lo;
      if ((unsigned)d0 < (unsigned)hstep) atomicAdd(&lhist[d0], 1);
      if ((unsigned)d1 < (unsigned)hstep) atomicAdd(&lhist[d1], 1);
      if ((unsigned)d2 < (unsigned)hstep) atomicAdd(&lhist[d2], 1);
      if ((unsigned)d3 < (unsigned)hstep) atomicAdd(&lhist[d3], 1);
    }
    for (; e < ee; e += 256) {
      int d = dstE[e] - lo;
      if ((unsigned)d < (unsigned)hstep) atomicAdd(&lhist[d], 1);
    }
    __syncthreads();
    for (int i = tid; i < hstep; i += 256) {
      int node = lo + i;
      if (node < N) partial[(size_t)g * N + node] = (unsigned short)lhist[i];
    }
    return;
  }

  constexpr int KS = FIN / 32;        // k-steps of 32
  constexpr int CPR = FIN / 8;        // 16B chunks per W row
  constexpr int NCHUNK = 128 * CPR;   // total 16B chunks (128 out-cols)

  unsigned short* wlds = (unsigned short*)smem;  // bf16 W, swizzled

  const int w    = tid >> 6;    // wave 0..3 -> rows [w*16, w*16+16)
  const int lane = tid & 63;
  const int cl   = lane & 15;   // A-row / D-col within tile
  const int grp  = lane >> 4;   // k-group / D-row-group
  const int n0   = (blockIdx.x - nhistb) * 64;

  const int arow = n0 + w * 16 + cl;
  const bool avalid = arow < N;

  // ---- A fragments: bf16 direct or fp32+convert ----
  short8 afrag[KS];
#pragma unroll
  for (int ks = 0; ks < KS; ++ks) {
    if constexpr (AB16) {
      short8 z = {0, 0, 0, 0, 0, 0, 0, 0};
      afrag[ks] = z;
      if (avalid) {
        const unsigned short* xb = (const unsigned short*)xin;
        afrag[ks] =
            *(const short8*)(xb + (size_t)arow * FIN + ks * 32 + grp * 8);
      }
    } else {
      float4 v0 = make_float4(0.f, 0.f, 0.f, 0.f), v1 = v0;
      if (avalid) {
        const float* xf = (const float*)xin;
        const float4* xp =
            (const float4*)(xf + (size_t)arow * FIN + ks * 32 + grp * 8);
        v0 = xp[0];
        v1 = xp[1];
      }
      union { short8 s8; unsigned u[4]; } af;
      af.u[0] = f2bf(v0.x) | (f2bf(v0.y) << 16);
      af.u[1] = f2bf(v0.z) | (f2bf(v0.w) << 16);
      af.u[2] = f2bf(v1.x) | (f2bf(v1.y) << 16);
      af.u[3] = f2bf(v1.z) | (f2bf(v1.w) << 16);
      afrag[ks] = af.s8;
    }
  }

  // ---- stage bf16 W -> LDS, XOR-swizzled 16B chunks ----
  const uint4* Wb4 = (const uint4*)Wb;
  for (int c = tid; c < NCHUNK; c += 256) {
    int row = c / CPR;           // CPR is pow2 -> shift
    int cc  = c & (CPR - 1);
    *(uint4*)&wlds[row * FIN + ((cc ^ (row & (CPR - 1))) * 8)] = Wb4[c];
  }
  __syncthreads();

  // ---- MFMA main: 8 col-tiles x KS k-steps; B-frags from LDS ----
  f32x4 acc[8];
#pragma unroll
  for (int ct = 0; ct < 8; ++ct) acc[ct] = (f32x4){0.f, 0.f, 0.f, 0.f};

  const int swz = cl & (CPR - 1);  // (ct*16+cl) & (CPR-1) == cl & (CPR-1)
#pragma unroll
  for (int ks = 0; ks < KS; ++ks) {
#pragma unroll
    for (int ct = 0; ct < 8; ++ct) {
      const unsigned short* bp =
          &wlds[(ct * 16 + cl) * FIN + (((ks * 4 + grp) ^ swz) * 8)];
      short8 bfrag = *(const short8*)bp;
      acc[ct] = __builtin_amdgcn_mfma_f32_16x16x32_bf16(afrag[ks], bfrag,
                                                        acc[ct], 0, 0, 0);
    }
  }

  // ---- epilogue: fused attention scores + packed bf16x2 h ----
  // lane's cols: head0 -> ct*16+cl (ct 0..3), head1 -> (ct-4)*16+cl (ct 4..7)
  float ai[8], aj[8];
#pragma unroll
  for (int ct = 0; ct < 8; ++ct) {
    int hd = ct >> 2;
    int cw = (ct & 3) * 16 + cl;
    ai[ct] = att[hd * 128 + cw];
    aj[ct] = att[hd * 128 + 64 + cw];
  }

#pragma unroll
  for (int r = 0; r < 4; ++r) {
    int node = n0 + w * 16 + grp * 4 + r;  // D row for this reg
    float s0i = 0.f, s0j = 0.f, s1i = 0.f, s1j = 0.f;
    unsigned wpk[4];
#pragma unroll
    for (int ct = 0; ct < 4; ++ct) {
      float v0 = acc[ct][r];      // head0, col ct*16+cl
      float v1 = acc[ct + 4][r];  // head1, same channel
      s0i += v0 * ai[ct];
      s0j += v0 * aj[ct];
      s1i += v1 * ai[ct + 4];
      s1j += v1 * aj[ct + 4];
      wpk[ct] = f2bf(v0) | (f2bf(v1) << 16);
    }
    // reduce the 16 channel-lanes of this group
#pragma unroll
    for (int off = 8; off; off >>= 1) {
      s0i += __shfl_xor(s0i, off, 64);
      s0j += __shfl_xor(s0j, off, 64);
      s1i += __shfl_xor(s1i, off, 64);
      s1j += __shfl_xor(s1j, off, 64);
    }
    if (node < N) {
#pragma unroll
      for (int ct = 0; ct < 4; ++ct)
        hq[(size_t)node * 64 + ct * 16 + cl] = wpk[ct];
      if (cl == 0) {
        si[node * 2 + 0] = s0i;
        si[node * 2 + 1] = s1i;
        sj[node * 2 + 0] = s0j;
        sj[node * 2 + 1] = s1j;
      }
    }
  }
}

// SINGLE-PASS merged scan: one walk over partial converts counts to
// exclusive stripe deltas IN PLACE while accumulating node totals; block
// scan + parallel lookback (flags = per-block totals) -> rowptr.
__global__ __launch_bounds__(256) void scan_full(
    unsigned short* __restrict__ partial, int* __restrict__ rowptr,
    int* __restrict__ flags, int N, int Eall, int nb) {
  __shared__ int ts[256];
  __shared__ int pre_s;
  const int b = blockIdx.x, t = threadIdx.x;
  const int base = b * 1024 + t * 4;   // N % 4 == 0
  int r0 = 0, r1 = 0, r2 = 0, r3 = 0;
  if (base < N) {
#pragma unroll 8
    for (int g = 0; g < HG; ++g) {
      unsigned long long* p =
          (unsigned long long*)&partial[(size_t)g * N + base];
      unsigned long long v = *p;
      *p = (unsigned long long)(unsigned short)r0 |
           ((unsigned long long)(unsigned short)r1 << 16) |
           ((unsigned long long)(unsigned short)r2 << 32) |
           ((unsigned long long)(unsigned short)r3 << 48);
      r0 += (int)(v & 0xffffu);
      r1 += (int)((v >> 16) & 0xffffu);
      r2 += (int)((v >> 32) & 0xffffu);
      r3 += (int)((v >> 48) & 0xffffu);
    }
  }
  const int tot = r0 + r1 + r2 + r3;
  ts[t] = tot;
  __syncthreads();
#pragma unroll
  for (int off = 1; off < 256; off <<= 1) {
    int x = (t >= off) ? ts[t - off] : 0;
    __syncthreads();
    ts[t] += x;
    __syncthreads();
  }
  const int run_local = ts[t] - tot;
  const int blktot = ts[255];
  if (t == 0)
    __hip_atomic_store(&flags[b], blktot, __ATOMIC_RELEASE,
                       __HIP_MEMORY_SCOPE_AGENT);
  __syncthreads();             // ts about to be reused
  if (t < b) {
    int v;
    do {
      v = __hip_atomic_load(&flags[t], __ATOMIC_ACQUIRE,
                            __HIP_MEMORY_SCOPE_AGENT);
    } while (v < 0);
    ts[t] = v;
  }
  __syncthreads();
  if (t == 0) {
    int acc = 0;
    for (int i = 0; i < b; ++i) acc += ts[i];
    pre_s = acc;
  }
  __syncthreads();
  int run = pre_s + run_local;
  if (base < N) {
    rowptr[base] = run;         run += r0;
    rowptr[base + 1] = run;     run += r1;
    rowptr[base + 2] = run;     run += r2;
    rowptr[base + 3] = run;
  }
  if (b == nb - 1 && t == 255) rowptr[N] = Eall;
}

// 1024-thread blocks. blocks[0,NSELF): self-loop z1 (coalesced stream);
// blocks[NSELF,NSELF+NHISTB): atomic-free scatter over the SAME contiguous
// stripe range the histogram counted. lcur = rowptr (L1-hot slice) + u16
// delta. Writes ONE 8B record {s, bf16w0|bf16w1} per edge at its exclusive
// position; accumulates z1 (fp32 w) over its edges.
__global__ __launch_bounds__(1024) void scatter_z(
    const int* __restrict__ srcE, const int* __restrict__ dstE,
    const unsigned short* __restrict__ partial, const int* __restrict__ rowptr,
    uint2* __restrict__ erec,
    const float2* __restrict__ si2, const float2* __restrict__ sj2,
    float* __restrict__ Zp, int E, int hstep, int N, int eper) {
  __shared__ __align__(16) int lcur[HRANGE_MAX];
  const int tid = threadIdx.x;
  float z0 = 0.f, z1 = 0.f;

  if ((int)blockIdx.x < NSELF) {
    // ---- self-loop z: coalesced stream over nodes ----
    for (int n = blockIdx.x * 1024 + tid; n < N; n += NSELF * 1024) {
      float2 a = si2[n], b = sj2[n];
      z0 += lrexp(a.x + b.x);
      z1 += lrexp(a.y + b.y);
    }
    block_zadd(z0, z1, Zp);
    return;
  }

  const int bid = blockIdx.x - NSELF;
  const int p = bid & (HP - 1);
  const int g = bid >> 3;
  const int lo = p * hstep;
  for (int i = tid; i < hstep; i += 1024) {
    int node = lo + i;
    lcur[i] = (node < N)
                  ? rowptr[node] + (int)partial[(size_t)g * N + node]
                  : 0;
  }
  __syncthreads();

  const int eb = g * eper;
  const int ee = min(E, eb + eper);
  int e = eb + tid;
  for (; e + 3 * 1024 < ee; e += 4 * 1024) {
    // 8 independent coalesced fetches in flight
    int d0 = dstE[e], d1 = dstE[e + 1024];
    int d2 = dstE[e + 2 * 1024], d3 = dstE[e + 3 * 1024];
    int s0 = srcE[e], s1 = srcE[e + 1024];
    int s2 = srcE[e + 2 * 1024], s3 = srcE[e + 3 * 1024];
    int t0 = d0 - lo, t1 = d1 - lo, t2 = d2 - lo, t3 = d3 - lo;
    if ((unsigned)t0 < (unsigned)hstep) {
      float2 siv = si2[d0], sjv = sj2[s0];
      float w0 = lrexp(siv.x + sjv.x), w1 = lrexp(siv.y + sjv.y);
      z0 += w0; z1 += w1;
      erec[atomicAdd(&lcur[t0], 1)] =
          make_uint2((unsigned)s0, f2bf(w0) | (f2bf(w1) << 16));
    }
    if ((unsigned)t1 < (unsigned)hstep) {
      float2 siv = si2[d1], sjv = sj2[s1];
      float w0 = lrexp(siv.x + sjv.x), w1 = lrexp(siv.y + sjv.y);
      z0 += w0; z1 += w1;
      erec[atomicAdd(&lcur[t1], 1)] =
          make_uint2((unsigned)s1, f2bf(w0) | (f2bf(w1) << 16));
    }
    if ((unsigned)t2 < (unsigned)hstep) {
      float2 siv = si2[d2], sjv = sj2[s2];
      float w0 = lrexp(siv.x + sjv.x), w1 = lrexp(siv.y + sjv.y);
      z0 += w0; z1 += w1;
      erec[atomicAdd(&lcur[t2], 1)] =
          make_uint2((unsigned)s2, f2bf(w0) | (f2bf(w1) << 16));
    }
    if ((unsigned)t3 < (unsigned)hstep) {
      float2 siv = si2[d3], sjv = sj2[s3];
      float w0 = lrexp(siv.x + sjv.x), w1 = lrexp(siv.y + sjv.y);
      z0 += w0; z1 += w1;
      erec[atomicAdd(&lcur[t3], 1)] =
          make_uint2((unsigned)s3, f2bf(w0) | (f2bf(w1) << 16));
    }
  }
  for (; e < ee; e += 1024) {
    int d = dstE[e];
    int dd = d - lo;
    if ((unsigned)dd < (unsigned)hstep) {
      int s = srcE[e];
      float2 siv = si2[d], sjv = sj2[s];
      float w0 = lrexp(siv.x + sjv.x), w1 = lrexp(siv.y + sjv.y);
      z0 += w0; z1 += w1;
      erec[atomicAdd(&lcur[dd], 1)] =
          make_uint2((unsigned)s, f2bf(w0) | (f2bf(w1) << 16));
    }
  }
  block_zadd(z0, z1, Zp);
}

// ROW-PARALLEL layer-2 weight refresh + fused z2: one wave per node,
// lanes cover the row's edges in parallel (d == n, wave-resident).
// w computed fp32 (summed into z2), stored bf16-packed. Self-loop z2
// contributed by lane 0 of each row's wave.
__global__ __launch_bounds__(256) void wgt2_z2(
    const int* __restrict__ rowptr, uint2* __restrict__ erec,
    const float2* __restrict__ si2, const float2* __restrict__ sj2,
    float* __restrict__ Zp, int N) {
  int lane = threadIdx.x & 63;
  int wid = (blockIdx.x * blockDim.x + threadIdx.x) >> 6;
  int nw = (gridDim.x * blockDim.x) >> 6;
  float z0 = 0.f, z1 = 0.f;
  for (int n0 = wid; n0 < N; n0 += nw) {
    int n = __builtin_amdgcn_readfirstlane(n0);
    int beg = rowptr[n], end = rowptr[n + 1];
    float2 siv = si2[n];
    if (lane == 0) {  // self-loop z2
      float2 jv = sj2[n];
      z0 += lrexp(siv.x + jv.x);
      z1 += lrexp(siv.y + jv.y);
    }
    for (int k = beg + lane; k < end; k += 64) {
      uint2 r = erec[k];
      float2 jv = sj2[(int)r.x];
      float w0 = lrexp(siv.x + jv.x);
      float w1 = lrexp(siv.y + jv.y);
      z0 += w0; z1 += w1;
      r.y = f2bf(w0) | (f2bf(w1) << 16);
      erec[k] = r;
    }
  }
  block_zadd(z0, z1, Zp);
}

// --- csr_aggregate helpers: 8B packed-record edge steps, deep-pipelined ---
__device__ __forceinline__ void edge8r(
    const uint2* __restrict__ erec, int k, const unsigned* __restrict__ hq,
    int lane, float& acc0, float& acc1) {
  // 8 record loads issue first; 8 hq gathers in flight; then 16 FMA.
  uint2 r0 = erec[k],     r1 = erec[k + 1], r2 = erec[k + 2], r3 = erec[k + 3];
  uint2 r4 = erec[k + 4], r5 = erec[k + 5], r6 = erec[k + 6], r7 = erec[k + 7];
  unsigned p0 = hq[(size_t)r0.x * 64 + lane];
  unsigned p1 = hq[(size_t)r1.x * 64 + lane];
  unsigned p2 = hq[(size_t)r2.x * 64 + lane];
  unsigned p3 = hq[(size_t)r3.x * 64 + lane];
  unsigned p4 = hq[(size_t)r4.x * 64 + lane];
  unsigned p5 = hq[(size_t)r5.x * 64 + lane];
  unsigned p6 = hq[(size_t)r6.x * 64 + lane];
  unsigned p7 = hq[(size_t)r7.x * 64 + lane];
  acc0 = fmaf(bflo(p0), bflo(r0.y), acc0);  acc1 = fmaf(bfhi(p0), bfhi(r0.y), acc1);
  acc0 = fmaf(bflo(p1), bflo(r1.y), acc0);  acc1 = fmaf(bfhi(p1), bfhi(r1.y), acc1);
  acc0 = fmaf(bflo(p2), bflo(r2.y), acc0);  acc1 = fmaf(bfhi(p2), bfhi(r2.y), acc1);
  acc0 = fmaf(bflo(p3), bflo(r3.y), acc0);  acc1 = fmaf(bfhi(p3), bfhi(r3.y), acc1);
  acc0 = fmaf(bflo(p4), bflo(r4.y), acc0);  acc1 = fmaf(bfhi(p4), bfhi(r4.y), acc1);
  acc0 = fmaf(bflo(p5), bflo(r5.y), acc0);  acc1 = fmaf(bfhi(p5), bfhi(r5.y), acc1);
  acc0 = fmaf(bflo(p6), bflo(r6.y), acc0);  acc1 = fmaf(bfhi(p6), bfhi(r6.y), acc1);
  acc0 = fmaf(bflo(p7), bflo(r7.y), acc0);  acc1 = fmaf(bfhi(p7), bfhi(r7.y), acc1);
}
__device__ __forceinline__ void edge4r(
    const uint2* __restrict__ erec, int k, const unsigned* __restrict__ hq,
    int lane, float& acc0, float& acc1) {
  uint2 r0 = erec[k], r1 = erec[k + 1], r2 = erec[k + 2], r3 = erec[k + 3];
  unsigned p0 = hq[(size_t)r0.x * 64 + lane];
  unsigned p1 = hq[(size_t)r1.x * 64 + lane];
  unsigned p2 = hq[(size_t)r2.x * 64 + lane];
  unsigned p3 = hq[(size_t)r3.x * 64 + lane];
  acc0 = fmaf(bflo(p0), bflo(r0.y), acc0);  acc1 = fmaf(bfhi(p0), bfhi(r0.y), acc1);
  acc0 = fmaf(bflo(p1), bflo(r1.y), acc0);  acc1 = fmaf(bfhi(p1), bfhi(r1.y), acc1);
  acc0 = fmaf(bflo(p2), bflo(r2.y), acc0);  acc1 = fmaf(bfhi(p2), bfhi(r2.y), acc1);
  acc0 = fmaf(bflo(p3), bflo(r3.y), acc0);  acc1 = fmaf(bfhi(p3), bfhi(r3.y), acc1);
}
__device__ __forceinline__ void edge1r(
    int s, float w0, float w1, const unsigned* __restrict__ hq, int lane,
    float& acc0, float& acc1) {
  unsigned p = hq[(size_t)s * 64 + lane];
  acc0 = fmaf(bflo(p), w0, acc0);
  acc1 = fmaf(bfhi(p), w1, acc1);
}

// one wave per dst node (scalarized): 8B packed edge records, inline
// self-loop term (fp32 weight), fused head-mean + bias (+relu).
// bf16_out: write bf16 (x2 intermediate, same RNE gemm2 would apply).
__global__ __launch_bounds__(256) void csr_aggregate(
    const int* __restrict__ rowptr, const uint2* __restrict__ erec,
    const unsigned* __restrict__ hq, const float2* __restrict__ si2,
    const float2* __restrict__ sj2, const float* __restrict__ Zp,
    const float* __restrict__ bias, void* __restrict__ out,
    int N, int do_relu, int bf16_out) {
  int lane = threadIdx.x & 63;
  int wid = (blockIdx.x * blockDim.x + threadIdx.x) >> 6;
  int nw = (gridDim.x * blockDim.x) >> 6;
  float z0 = 1.f / (Zp[0] + 1e-10f);
  float z1 = 1.f / (Zp[1] + 1e-10f);
  float bv = bias[lane];
  for (int n0 = wid; n0 < N; n0 += nw) {
    // n is wave-uniform; force SGPR so the rowptr/erec chain is scalar
    int n = __builtin_amdgcn_readfirstlane(n0);
    int beg = rowptr[n], end = rowptr[n + 1];
    // self-loop term (src = dst = n)
    float2 siv = si2[n];
    float2 jv = sj2[n];
    float acc0 = 0.f, acc1 = 0.f;
    edge1r(n, lrexp(siv.x + jv.x), lrexp(siv.y + jv.y), hq, lane, acc0, acc1);
    int k = beg;
    for (; k + 8 <= end; k += 8) edge8r(erec, k, hq, lane, acc0, acc1);
    if (k + 4 <= end) { edge4r(erec, k, hq, lane, acc0, acc1); k += 4; }
    for (; k < end; ++k) {
      uint2 r = erec[k];
      edge1r((int)r.x, bflo(r.y), bfhi(r.y), hq, lane, acc0, acc1);
    }
    float r = 0.5f * (acc0 * z0 + acc1 * z1) + bv;
    if (do_relu) r = fmaxf(r, 0.f);
    if (bf16_out)
      ((unsigned short*)out)[(size_t)n * 64 + lane] = (unsigned short)f2bf(r);
    else
      ((float*)out)[(size_t)n * 64 + lane] = r;
  }
}

extern "C" void kernel_launch(void* const* d_in, const int* in_sizes, int n_in,
                              void* d_out, int out_size, void* d_ws, size_t ws_size,
                              hipStream_t stream) {
  const float* x    = (const float*)d_in[0];
  const int*   ei   = (const int*)d_in[1];   // [2, E] int32
  const float* W1   = (const float*)d_in[2];
  const float* att1 = (const float*)d_in[3];
  const float* b1   = (const float*)d_in[4];
  const float* W2   = (const float*)d_in[5];
  const float* att2 = (const float*)d_in[6];
  const float* b2   = (const float*)d_in[7];
  float* out = (float*)d_out;

  const int N = in_sizes[0] / 128;   // 50000
  const int E = in_sizes[1] / 2;     // 800000
  const int* srcE = ei;
  const int* dstE = ei + E;

  // workspace layout (16B-sensitive arrays aligned)
  unsigned* hq = (unsigned*)d_ws;                 // N*64 packed bf16x2
  float* si    = (float*)(hq + (size_t)N * 64);   // N*2
  float* sj    = si + (size_t)N * 2;              // N*2
  float* Z     = sj + (size_t)N * 2;              // 4 (L1: Z[0..1], L2: Z[2..3])
  float* x2    = Z + 4;                           // N*64 f32 region
  unsigned short* partial = (unsigned short*)x2;  // HG*N u16 (dies pre-x2)
  unsigned short* x2b = (unsigned short*)x2;      // N*64 bf16 (after scatter)
  int* rowptr  = (int*)(x2 + (size_t)N * 64);     // N+1
  int* flags   = rowptr + (N + 1);                // 64 lookback flags
  uintptr_t ep = ((uintptr_t)(flags + 64) + 15) & ~(uintptr_t)15;
  uint2* erec  = (uint2*)ep;                      // E packed {s, bf16 w pair}
  unsigned short* wbf1 = (unsigned short*)(erec + E);  // 128*128 bf16 W1
  unsigned short* wbf2 = wbf1 + 128 * 128;             // 128*64 bf16 W2

  dim3 blk(256);
  dim3 blk1k(1024);
  int nb = (N + 1023) / 1024;      // 49 scan blocks (<= 64)
  int ntiles = (N + 63) / 64;
  int hstep = (N + HP - 1) / HP;   // 6250 <= HRANGE_MAX
  int eper  = (E + HG - 1) / HG;   // contiguous stripe width (12500)

  // 0) W -> bf16 + zero Z + flags=-1
  init_ws<<<64, blk, 0, stream>>>(W1, W2, wbf1, wbf2, Z, flags);
  // 1) hist (blocks[0,512), atomic-free, u16 flush) + gemm1 (MFMA, fp32 A)
  gemm_mfma<128, false><<<NHISTB + ntiles, blk, 0, stream>>>(
      x, wbf1, att1, hq, si, sj, N, dstE, partial, E, NHISTB, hstep, eper);
  // 2) single-pass merged scan (deltas in place + lookback rowptr)
  scan_full<<<nb, blk, 0, stream>>>(partial, rowptr, flags, N, E, nb);
  // 3) self-loop z1 + atomic-free scatter w/ 8B packed records + fused z1
  scatter_z<<<NSELF + NHISTB, blk1k, 0, stream>>>(
      srcE, dstE, partial, rowptr, erec, (const float2*)si,
      (const float2*)sj, Z, E, hstep, N, eper);
  // 4) layer-1 aggregation -> x2 (bf16 out; 8-deep pipelined; relu fused)
  csr_aggregate<<<4096, blk, 0, stream>>>(rowptr, erec, hq,
                                          (const float2*)si, (const float2*)sj,
                                          Z, b1, x2b, N, 1, 1);
  // 5) gemm2 (MFMA, bf16 A; nhistb=0: hist branch never taken)
  gemm_mfma<64, true><<<ntiles, blk, 0, stream>>>(
      x2b, wbf2, att2, hq, si, sj, N, dstE, partial, E, 0, hstep, eper);
  // 6) row-parallel layer-2 weight refresh + fused z2 (incl. self-loops)
  wgt2_z2<<<4096, blk, 0, stream>>>(rowptr, erec, (const float2*)si,
                                    (const float2*)sj, Z + 2, N);
  // 7) layer-2 aggregation -> out (fp32)
  csr_aggregate<<<4096, blk, 0, stream>>>(rowptr, erec, hq,
                                          (const float2*)si, (const float2*)sj,
                                          Z + 2, b2, out, N, 0, 0);
}

// Round 13
// 231.469 us; speedup vs baseline: 1.4226x; 1.4226x over previous
//
#include <hip/hip_runtime.h>
#include <hip/hip_bf16.h>
#include <math.h>

// ---------------------------------------------------------------------------
// GAT 2-layer forward. CSR aggregation, bf16 gather table, precomputed
// per-edge attention weights in PACKED 8B records {u16 src | u16 dst,
// bf16w0|bf16w1}  (N=50000 < 65536 -> node ids fit u16).
// bf16 MFMA GEMM (W staged in LDS, XOR-swizzled). CSR build FULLY ATOMIC-FREE
// (global): per-(partition,stripe) LDS histograms -> u16 stripe counts ->
// SINGLE-PASS merged scan (deg-sum + in-place exclusive stripe deltas +
// lookback block prefix) -> LDS-cursor placement (rowptr + u16 delta),
// ONE 8B store per edge. Z denominators FUSED into weight-producing passes
// (fp32, pre-rounding). x2 intermediate stored bf16. Layer-2 weight refresh
// is STREAMING edge-parallel (round-12's row-parallel variant measured 10x
// slower: short rows -> idle lanes + unpipelined dependent chains).
//
//   0) init_ws: W1/W2 -> bf16 copies; zero Z; flags = -1
//   1) gemm_mfma<128,fp32 A>: blocks[0,512) = hist (8 partitions x 64
//      contiguous-range stripes, 25KB LDS, u16 flush); rest = MFMA gemm1.
//   2) scan_full (49 blocks): merged deg-sum + in-place deltas + lookback.
//   3) scatter_z (1024-thr): blocks[0,16)=self-loop z1; blocks[16,528) =
//      atomic-free scatter (lcur = rowptr + u16 delta), packs 8B records,
//      fused z1 (fp32 w) over its edges.
//   4) csr_aggregate -> x2 (bf16 out): 8-deep pipelined gather loop.
//   5) gemm_mfma<64,bf16 A> grid=ntiles (pure gemm2)
//   6) z_wgt2 (1024-thr): blocks[0,16) = self-loop z2; rest = STREAMING
//      record weight refresh (8B RMW, coalesced; s,d unpacked from r.x)
//      + fused z2 sum.
//   7) csr_aggregate -> out (fp32)
//
// MFMA layout (HW-verified m89): A: lane holds A[l&15][(l>>4)*8+j];
// B: B[(l>>4)*8+j][l&15]; D: row=(l>>4)*4+reg, col=l&15.
// LDS swizzle: W row r, 16B-chunk c at position c ^ (r & CPR-1).
// u16 safety: stripe count <= Eper=12500; per-row delta <= deg(n); node
// ids < N=50000 < 65536. Lookback: 49 co-resident blocks, publish-first.
// Numerics: record weights bf16 (validated round 12: absmax unchanged);
// z sums fp32 from unrounded weights.
// ---------------------------------------------------------------------------

#define HP 8             // dst partitions
#define HG 64            // edge stripes
#define NHISTB (HP * HG) // 512 hist/scatter blocks
#define HRANGE_MAX 6272  // compile-time LDS bound for one partition's counters
#define NSELF 16         // self-loop z blocks (1024 threads each)
#define NWGT  256        // record-refresh blocks in z_wgt2 (1024 threads)

using short8 = __attribute__((ext_vector_type(8))) short;
using f32x4  = __attribute__((ext_vector_type(4))) float;

__device__ __forceinline__ unsigned f2bf(float x) {  // fp32 -> bf16 (RNE)
  unsigned u = __float_as_uint(x);
  return (u + 0x7fffu + ((u >> 16) & 1u)) >> 16;
}
__device__ __forceinline__ float bflo(unsigned p) { return __uint_as_float(p << 16); }
__device__ __forceinline__ float bfhi(unsigned p) { return __uint_as_float(p & 0xffff0000u); }
__device__ __forceinline__ float lrexp(float a) {   // exp(leaky_relu(a, 0.2))
  a = a >= 0.f ? a : 0.2f * a;
  return __expf(a);
}

// block-wide z reduction (up to 16 waves) + one atomicAdd pair per block
__device__ __forceinline__ void block_zadd(float z0, float z1,
                                           float* __restrict__ Zp) {
  __shared__ float r0[16], r1[16];
  int lane = threadIdx.x & 63, w = threadIdx.x >> 6;
  int nw = blockDim.x >> 6;
#pragma unroll
  for (int off = 32; off; off >>= 1) {
    z0 += __shfl_down(z0, off, 64);
    z1 += __shfl_down(z1, off, 64);
  }
  if (lane == 0) { r0[w] = z0; r1[w] = z1; }
  __syncthreads();
  if (threadIdx.x == 0) {
    float s0 = 0.f, s1 = 0.f;
    for (int i = 0; i < nw; ++i) { s0 += r0[i]; s1 += r1[i]; }
    atomicAdd(&Zp[0], s0);
    atomicAdd(&Zp[1], s1);
  }
}

// W -> bf16 copies + zero Z + lookback flags = -1
__global__ __launch_bounds__(256) void init_ws(
    const float* __restrict__ W1, const float* __restrict__ W2,
    unsigned short* __restrict__ wbf1, unsigned short* __restrict__ wbf2,
    float* __restrict__ Z, int* __restrict__ flags) {
  int tid = blockIdx.x * 256 + threadIdx.x;
  int stride = gridDim.x * 256;
  for (int i = tid; i < 128 * 128; i += stride)
    wbf1[i] = (unsigned short)f2bf(W1[i]);
  for (int i = tid; i < 128 * 64; i += stride)
    wbf2[i] = (unsigned short)f2bf(W2[i]);
  if (tid < 4) Z[tid] = 0.f;
  if (tid < 64) flags[tid] = -1;
}

// MFMA GEMM (h = x @ W^T) + fused attention scores + bf16 pack.
// AB16: A operand is bf16 (x2 intermediate); else fp32 with RNE convert.
// blocks < nhistb run the atomic-free LDS-privatized degree histogram.
template <int FIN, bool AB16>
__global__ __launch_bounds__(256) void gemm_mfma(
    const void* __restrict__ xin, const unsigned short* __restrict__ Wb,
    const float* __restrict__ att, unsigned* __restrict__ hq,
    float* __restrict__ si, float* __restrict__ sj,
    int N,
    const int* __restrict__ dstE, unsigned short* __restrict__ partial,
    int E, int nhistb, int hstep, int eper) {
  const int tid = threadIdx.x;

  constexpr int WB = 128 * FIN * 2;  // bf16 W tile bytes
  constexpr int SMEM = (WB > HRANGE_MAX * 4) ? WB : HRANGE_MAX * 4;
  __shared__ __align__(16) unsigned char smem[SMEM];

  if ((int)blockIdx.x < nhistb) {
    // ---- atomic-free histogram: partition p, stripe g (contiguous) ----
    int* lhist = (int*)smem;
    const int p = blockIdx.x & (HP - 1);
    const int g = blockIdx.x >> 3;        // stripe 0..HG-1
    const int lo = p * hstep;
    for (int i = tid; i < hstep; i += 256) lhist[i] = 0;
    __syncthreads();
    const int eb = g * eper;
    const int ee = min(E, eb + eper);
    int e = eb + tid;
    for (; e + 3 * 256 < ee; e += 4 * 256) {
      int d0 = dstE[e] - lo;
      int d1 = dstE[e + 256] - lo;
      int d2 = dstE[e + 2 * 256] - lo;
      int d3 = dstE[e + 3 * 256] - lo;
      if ((unsigned)d0 < (unsigned)hstep) atomicAdd(&lhist[d0], 1);
      if ((unsigned)d1 < (unsigned)hstep) atomicAdd(&lhist[d1], 1);
      if ((unsigned)d2 < (unsigned)hstep) atomicAdd(&lhist[d2], 1);
      if ((unsigned)d3 < (unsigned)hstep) atomicAdd(&lhist[d3], 1);
    }
    for (; e < ee; e += 256) {
      int d = dstE[e] - lo;
      if ((unsigned)d < (unsigned)hstep) atomicAdd(&lhist[d], 1);
    }
    __syncthreads();
    for (int i = tid; i < hstep; i += 256) {
      int node = lo + i;
      if (node < N) partial[(size_t)g * N + node] = (unsigned short)lhist[i];
    }
    return;
  }

  constexpr int KS = FIN / 32;        // k-steps of 32
  constexpr int CPR = FIN / 8;        // 16B chunks per W row
  constexpr int NCHUNK = 128 * CPR;   // total 16B chunks (128 out-cols)

  unsigned short* wlds = (unsigned short*)smem;  // bf16 W, swizzled

  const int w    = tid >> 6;    // wave 0..3 -> rows [w*16, w*16+16)
  const int lane = tid & 63;
  const int cl   = lane & 15;   // A-row / D-col within tile
  const int grp  = lane >> 4;   // k-group / D-row-group
  const int n0   = (blockIdx.x - nhistb) * 64;

  const int arow = n0 + w * 16 + cl;
  const bool avalid = arow < N;

  // ---- A fragments: bf16 direct or fp32+convert ----
  short8 afrag[KS];
#pragma unroll
  for (int ks = 0; ks < KS; ++ks) {
    if constexpr (AB16) {
      short8 z = {0, 0, 0, 0, 0, 0, 0, 0};
      afrag[ks] = z;
      if (avalid) {
        const unsigned short* xb = (const unsigned short*)xin;
        afrag[ks] =
            *(const short8*)(xb + (size_t)arow * FIN + ks * 32 + grp * 8);
      }
    } else {
      float4 v0 = make_float4(0.f, 0.f, 0.f, 0.f), v1 = v0;
      if (avalid) {
        const float* xf = (const float*)xin;
        const float4* xp =
            (const float4*)(xf + (size_t)arow * FIN + ks * 32 + grp * 8);
        v0 = xp[0];
        v1 = xp[1];
      }
      union { short8 s8; unsigned u[4]; } af;
      af.u[0] = f2bf(v0.x) | (f2bf(v0.y) << 16);
      af.u[1] = f2bf(v0.z) | (f2bf(v0.w) << 16);
      af.u[2] = f2bf(v1.x) | (f2bf(v1.y) << 16);
      af.u[3] = f2bf(v1.z) | (f2bf(v1.w) << 16);
      afrag[ks] = af.s8;
    }
  }

  // ---- stage bf16 W -> LDS, XOR-swizzled 16B chunks ----
  const uint4* Wb4 = (const uint4*)Wb;
  for (int c = tid; c < NCHUNK; c += 256) {
    int row = c / CPR;           // CPR is pow2 -> shift
    int cc  = c & (CPR - 1);
    *(uint4*)&wlds[row * FIN + ((cc ^ (row & (CPR - 1))) * 8)] = Wb4[c];
  }
  __syncthreads();

  // ---- MFMA main: 8 col-tiles x KS k-steps; B-frags from LDS ----
  f32x4 acc[8];
#pragma unroll
  for (int ct = 0; ct < 8; ++ct) acc[ct] = (f32x4){0.f, 0.f, 0.f, 0.f};

  const int swz = cl & (CPR - 1);  // (ct*16+cl) & (CPR-1) == cl & (CPR-1)
#pragma unroll
  for (int ks = 0; ks < KS; ++ks) {
#pragma unroll
    for (int ct = 0; ct < 8; ++ct) {
      const unsigned short* bp =
          &wlds[(ct * 16 + cl) * FIN + (((ks * 4 + grp) ^ swz) * 8)];
      short8 bfrag = *(const short8*)bp;
      acc[ct] = __builtin_amdgcn_mfma_f32_16x16x32_bf16(afrag[ks], bfrag,
                                                        acc[ct], 0, 0, 0);
    }
  }

  // ---- epilogue: fused attention scores + packed bf16x2 h ----
  // lane's cols: head0 -> ct*16+cl (ct 0..3), head1 -> (ct-4)*16+cl (ct 4..7)
  float ai[8], aj[8];
#pragma unroll
  for (int ct = 0; ct < 8; ++ct) {
    int hd = ct >> 2;
    int cw = (ct & 3) * 16 + cl;
    ai[ct] = att[hd * 128 + cw];
    aj[ct] = att[hd * 128 + 64 + cw];
  }

#pragma unroll
  for (int r = 0; r < 4; ++r) {
    int node = n0 + w * 16 + grp * 4 + r;  // D row for this reg
    float s0i = 0.f, s0j = 0.f, s1i = 0.f, s1j = 0.f;
    unsigned wpk[4];
#pragma unroll
    for (int ct = 0; ct < 4; ++ct) {
      float v0 = acc[ct][r];      // head0, col ct*16+cl
      float v1 = acc[ct + 4][r];  // head1, same channel
      s0i += v0 * ai[ct];
      s0j += v0 * aj[ct];
      s1i += v1 * ai[ct + 4];
      s1j += v1 * aj[ct + 4];
      wpk[ct] = f2bf(v0) | (f2bf(v1) << 16);
    }
    // reduce the 16 channel-lanes of this group
#pragma unroll
    for (int off = 8; off; off >>= 1) {
      s0i += __shfl_xor(s0i, off, 64);
      s0j += __shfl_xor(s0j, off, 64);
      s1i += __shfl_xor(s1i, off, 64);
      s1j += __shfl_xor(s1j, off, 64);
    }
    if (node < N) {
#pragma unroll
      for (int ct = 0; ct < 4; ++ct)
        hq[(size_t)node * 64 + ct * 16 + cl] = wpk[ct];
      if (cl == 0) {
        si[node * 2 + 0] = s0i;
        si[node * 2 + 1] = s1i;
        sj[node * 2 + 0] = s0j;
        sj[node * 2 + 1] = s1j;
      }
    }
  }
}

// SINGLE-PASS merged scan: one walk over partial converts counts to
// exclusive stripe deltas IN PLACE while accumulating node totals; block
// scan + parallel lookback (flags = per-block totals) -> rowptr.
__global__ __launch_bounds__(256) void scan_full(
    unsigned short* __restrict__ partial, int* __restrict__ rowptr,
    int* __restrict__ flags, int N, int Eall, int nb) {
  __shared__ int ts[256];
  __shared__ int pre_s;
  const int b = blockIdx.x, t = threadIdx.x;
  const int base = b * 1024 + t * 4;   // N % 4 == 0
  int r0 = 0, r1 = 0, r2 = 0, r3 = 0;
  if (base < N) {
#pragma unroll 8
    for (int g = 0; g < HG; ++g) {
      unsigned long long* p =
          (unsigned long long*)&partial[(size_t)g * N + base];
      unsigned long long v = *p;
      *p = (unsigned long long)(unsigned short)r0 |
           ((unsigned long long)(unsigned short)r1 << 16) |
           ((unsigned long long)(unsigned short)r2 << 32) |
           ((unsigned long long)(unsigned short)r3 << 48);
      r0 += (int)(v & 0xffffu);
      r1 += (int)((v >> 16) & 0xffffu);
      r2 += (int)((v >> 32) & 0xffffu);
      r3 += (int)((v >> 48) & 0xffffu);
    }
  }
  const int tot = r0 + r1 + r2 + r3;
  ts[t] = tot;
  __syncthreads();
#pragma unroll
  for (int off = 1; off < 256; off <<= 1) {
    int x = (t >= off) ? ts[t - off] : 0;
    __syncthreads();
    ts[t] += x;
    __syncthreads();
  }
  const int run_local = ts[t] - tot;
  const int blktot = ts[255];
  if (t == 0)
    __hip_atomic_store(&flags[b], blktot, __ATOMIC_RELEASE,
                       __HIP_MEMORY_SCOPE_AGENT);
  __syncthreads();             // ts about to be reused
  if (t < b) {
    int v;
    do {
      v = __hip_atomic_load(&flags[t], __ATOMIC_ACQUIRE,
                            __HIP_MEMORY_SCOPE_AGENT);
    } while (v < 0);
    ts[t] = v;
  }
  __syncthreads();
  if (t == 0) {
    int acc = 0;
    for (int i = 0; i < b; ++i) acc += ts[i];
    pre_s = acc;
  }
  __syncthreads();
  int run = pre_s + run_local;
  if (base < N) {
    rowptr[base] = run;         run += r0;
    rowptr[base + 1] = run;     run += r1;
    rowptr[base + 2] = run;     run += r2;
    rowptr[base + 3] = run;
  }
  if (b == nb - 1 && t == 255) rowptr[N] = Eall;
}

// pack helpers for 8B records: x = src | (dst<<16), y = bf16 w pair
__device__ __forceinline__ uint2 mkrec(int s, int d, float w0, float w1) {
  return make_uint2((unsigned)s | ((unsigned)d << 16),
                    f2bf(w0) | (f2bf(w1) << 16));
}

// 1024-thread blocks. blocks[0,NSELF): self-loop z1 (coalesced stream);
// blocks[NSELF,NSELF+NHISTB): atomic-free scatter over the SAME contiguous
// stripe range the histogram counted. lcur = rowptr (L1-hot slice) + u16
// delta. Writes ONE 8B record per edge at its exclusive position;
// accumulates z1 (fp32 w) over its edges.
__global__ __launch_bounds__(1024) void scatter_z(
    const int* __restrict__ srcE, const int* __restrict__ dstE,
    const unsigned short* __restrict__ partial, const int* __restrict__ rowptr,
    uint2* __restrict__ erec,
    const float2* __restrict__ si2, const float2* __restrict__ sj2,
    float* __restrict__ Zp, int E, int hstep, int N, int eper) {
  __shared__ __align__(16) int lcur[HRANGE_MAX];
  const int tid = threadIdx.x;
  float z0 = 0.f, z1 = 0.f;

  if ((int)blockIdx.x < NSELF) {
    // ---- self-loop z: coalesced stream over nodes ----
    for (int n = blockIdx.x * 1024 + tid; n < N; n += NSELF * 1024) {
      float2 a = si2[n], b = sj2[n];
      z0 += lrexp(a.x + b.x);
      z1 += lrexp(a.y + b.y);
    }
    block_zadd(z0, z1, Zp);
    return;
  }

  const int bid = blockIdx.x - NSELF;
  const int p = bid & (HP - 1);
  const int g = bid >> 3;
  const int lo = p * hstep;
  for (int i = tid; i < hstep; i += 1024) {
    int node = lo + i;
    lcur[i] = (node < N)
                  ? rowptr[node] + (int)partial[(size_t)g * N + node]
                  : 0;
  }
  __syncthreads();

  const int eb = g * eper;
  const int ee = min(E, eb + eper);
  int e = eb + tid;
  for (; e + 3 * 1024 < ee; e += 4 * 1024) {
    // 8 independent coalesced fetches in flight
    int d0 = dstE[e], d1 = dstE[e + 1024];
    int d2 = dstE[e + 2 * 1024], d3 = dstE[e + 3 * 1024];
    int s0 = srcE[e], s1 = srcE[e + 1024];
    int s2 = srcE[e + 2 * 1024], s3 = srcE[e + 3 * 1024];
    int t0 = d0 - lo, t1 = d1 - lo, t2 = d2 - lo, t3 = d3 - lo;
    if ((unsigned)t0 < (unsigned)hstep) {
      float2 siv = si2[d0], sjv = sj2[s0];
      float w0 = lrexp(siv.x + sjv.x), w1 = lrexp(siv.y + sjv.y);
      z0 += w0; z1 += w1;
      erec[atomicAdd(&lcur[t0], 1)] = mkrec(s0, d0, w0, w1);
    }
    if ((unsigned)t1 < (unsigned)hstep) {
      float2 siv = si2[d1], sjv = sj2[s1];
      float w0 = lrexp(siv.x + sjv.x), w1 = lrexp(siv.y + sjv.y);
      z0 += w0; z1 += w1;
      erec[atomicAdd(&lcur[t1], 1)] = mkrec(s1, d1, w0, w1);
    }
    if ((unsigned)t2 < (unsigned)hstep) {
      float2 siv = si2[d2], sjv = sj2[s2];
      float w0 = lrexp(siv.x + sjv.x), w1 = lrexp(siv.y + sjv.y);
      z0 += w0; z1 += w1;
      erec[atomicAdd(&lcur[t2], 1)] = mkrec(s2, d2, w0, w1);
    }
    if ((unsigned)t3 < (unsigned)hstep) {
      float2 siv = si2[d3], sjv = sj2[s3];
      float w0 = lrexp(siv.x + sjv.x), w1 = lrexp(siv.y + sjv.y);
      z0 += w0; z1 += w1;
      erec[atomicAdd(&lcur[t3], 1)] = mkrec(s3, d3, w0, w1);
    }
  }
  for (; e < ee; e += 1024) {
    int d = dstE[e];
    int dd = d - lo;
    if ((unsigned)dd < (unsigned)hstep) {
      int s = srcE[e];
      float2 siv = si2[d], sjv = sj2[s];
      float w0 = lrexp(siv.x + sjv.x), w1 = lrexp(siv.y + sjv.y);
      z0 += w0; z1 += w1;
      erec[atomicAdd(&lcur[dd], 1)] = mkrec(s, d, w0, w1);
    }
  }
  block_zadd(z0, z1, Zp);
}

// 1024-thread blocks. blocks[0,NSELF): self-loop z2; blocks[NSELF,+NWGT):
// STREAMING record weight refresh for layer 2 (8B RMW, coalesced; s,d
// unpacked from r.x) with fused z2 accumulation.
__global__ __launch_bounds__(1024) void z_wgt2(
    const float2* __restrict__ si2, const float2* __restrict__ sj2,
    float* __restrict__ Zp, uint2* __restrict__ erec, int E, int N) {
  const int tid = threadIdx.x;
  float z0 = 0.f, z1 = 0.f;
  if ((int)blockIdx.x < NSELF) {
    for (int n = blockIdx.x * 1024 + tid; n < N; n += NSELF * 1024) {
      float2 a = si2[n], b = sj2[n];
      z0 += lrexp(a.x + b.x);
      z1 += lrexp(a.y + b.y);
    }
  } else {
    int k = (blockIdx.x - NSELF) * 1024 + tid;
    for (; k < E; k += NWGT * 1024) {
      uint2 r = erec[k];
      int s = (int)(r.x & 0xffffu);
      int d = (int)(r.x >> 16);
      float2 siv = si2[d];
      float2 sjv = sj2[s];
      float w0 = lrexp(siv.x + sjv.x);
      float w1 = lrexp(siv.y + sjv.y);
      z0 += w0; z1 += w1;
      r.y = f2bf(w0) | (f2bf(w1) << 16);
      erec[k] = r;
    }
  }
  block_zadd(z0, z1, Zp);
}

// --- csr_aggregate helpers: 8B packed-record edge steps, deep-pipelined ---
__device__ __forceinline__ void edge8r(
    const uint2* __restrict__ erec, int k, const unsigned* __restrict__ hq,
    int lane, float& acc0, float& acc1) {
  // 8 record loads issue first; 8 hq gathers in flight; then 16 FMA.
  uint2 r0 = erec[k],     r1 = erec[k + 1], r2 = erec[k + 2], r3 = erec[k + 3];
  uint2 r4 = erec[k + 4], r5 = erec[k + 5], r6 = erec[k + 6], r7 = erec[k + 7];
  unsigned p0 = hq[(size_t)(r0.x & 0xffffu) * 64 + lane];
  unsigned p1 = hq[(size_t)(r1.x & 0xffffu) * 64 + lane];
  unsigned p2 = hq[(size_t)(r2.x & 0xffffu) * 64 + lane];
  unsigned p3 = hq[(size_t)(r3.x & 0xffffu) * 64 + lane];
  unsigned p4 = hq[(size_t)(r4.x & 0xffffu) * 64 + lane];
  unsigned p5 = hq[(size_t)(r5.x & 0xffffu) * 64 + lane];
  unsigned p6 = hq[(size_t)(r6.x & 0xffffu) * 64 + lane];
  unsigned p7 = hq[(size_t)(r7.x & 0xffffu) * 64 + lane];
  acc0 = fmaf(bflo(p0), bflo(r0.y), acc0);  acc1 = fmaf(bfhi(p0), bfhi(r0.y), acc1);
  acc0 = fmaf(bflo(p1), bflo(r1.y), acc0);  acc1 = fmaf(bfhi(p1), bfhi(r1.y), acc1);
  acc0 = fmaf(bflo(p2), bflo(r2.y), acc0);  acc1 = fmaf(bfhi(p2), bfhi(r2.y), acc1);
  acc0 = fmaf(bflo(p3), bflo(r3.y), acc0);  acc1 = fmaf(bfhi(p3), bfhi(r3.y), acc1);
  acc0 = fmaf(bflo(p4), bflo(r4.y), acc0);  acc1 = fmaf(bfhi(p4), bfhi(r4.y), acc1);
  acc0 = fmaf(bflo(p5), bflo(r5.y), acc0);  acc1 = fmaf(bfhi(p5), bfhi(r5.y), acc1);
  acc0 = fmaf(bflo(p6), bflo(r6.y), acc0);  acc1 = fmaf(bfhi(p6), bfhi(r6.y), acc1);
  acc0 = fmaf(bflo(p7), bflo(r7.y), acc0);  acc1 = fmaf(bfhi(p7), bfhi(r7.y), acc1);
}
__device__ __forceinline__ void edge4r(
    const uint2* __restrict__ erec, int k, const unsigned* __restrict__ hq,
    int lane, float& acc0, float& acc1) {
  uint2 r0 = erec[k], r1 = erec[k + 1], r2 = erec[k + 2], r3 = erec[k + 3];
  unsigned p0 = hq[(size_t)(r0.x & 0xffffu) * 64 + lane];
  unsigned p1 = hq[(size_t)(r1.x & 0xffffu) * 64 + lane];
  unsigned p2 = hq[(size_t)(r2.x & 0xffffu) * 64 + lane];
  unsigned p3 = hq[(size_t)(r3.x & 0xffffu) * 64 + lane];
  acc0 = fmaf(bflo(p0), bflo(r0.y), acc0);  acc1 = fmaf(bfhi(p0), bfhi(r0.y), acc1);
  acc0 = fmaf(bflo(p1), bflo(r1.y), acc0);  acc1 = fmaf(bfhi(p1), bfhi(r1.y), acc1);
  acc0 = fmaf(bflo(p2), bflo(r2.y), acc0);  acc1 = fmaf(bfhi(p2), bfhi(r2.y), acc1);
  acc0 = fmaf(bflo(p3), bflo(r3.y), acc0);  acc1 = fmaf(bfhi(p3), bfhi(r3.y), acc1);
}
__device__ __forceinline__ void edge1r(
    int s, float w0, float w1, const unsigned* __restrict__ hq, int lane,
    float& acc0, float& acc1) {
  unsigned p = hq[(size_t)s * 64 + lane];
  acc0 = fmaf(bflo(p), w0, acc0);
  acc1 = fmaf(bfhi(p), w1, acc1);
}

// one wave per dst node (scalarized): 8B packed edge records, inline
// self-loop term (fp32 weight), fused head-mean + bias (+relu).
// bf16_out: write bf16 (x2 intermediate, same RNE gemm2 would apply).
__global__ __launch_bounds__(256) void csr_aggregate(
    const int* __restrict__ rowptr, const uint2* __restrict__ erec,
    const unsigned* __restrict__ hq, const float2* __restrict__ si2,
    const float2* __restrict__ sj2, const float* __restrict__ Zp,
    const float* __restrict__ bias, void* __restrict__ out,
    int N, int do_relu, int bf16_out) {
  int lane = threadIdx.x & 63;
  int wid = (blockIdx.x * blockDim.x + threadIdx.x) >> 6;
  int nw = (gridDim.x * blockDim.x) >> 6;
  float z0 = 1.f / (Zp[0] + 1e-10f);
  float z1 = 1.f / (Zp[1] + 1e-10f);
  float bv = bias[lane];
  for (int n0 = wid; n0 < N; n0 += nw) {
    // n is wave-uniform; force SGPR so the rowptr/erec chain is scalar
    int n = __builtin_amdgcn_readfirstlane(n0);
    int beg = rowptr[n], end = rowptr[n + 1];
    // self-loop term (src = dst = n)
    float2 siv = si2[n];
    float2 jv = sj2[n];
    float acc0 = 0.f, acc1 = 0.f;
    edge1r(n, lrexp(siv.x + jv.x), lrexp(siv.y + jv.y), hq, lane, acc0, acc1);
    int k = beg;
    for (; k + 8 <= end; k += 8) edge8r(erec, k, hq, lane, acc0, acc1);
    if (k + 4 <= end) { edge4r(erec, k, hq, lane, acc0, acc1); k += 4; }
    for (; k < end; ++k) {
      uint2 r = erec[k];
      edge1r((int)(r.x & 0xffffu), bflo(r.y), bfhi(r.y), hq, lane, acc0, acc1);
    }
    float r = 0.5f * (acc0 * z0 + acc1 * z1) + bv;
    if (do_relu) r = fmaxf(r, 0.f);
    if (bf16_out)
      ((unsigned short*)out)[(size_t)n * 64 + lane] = (unsigned short)f2bf(r);
    else
      ((float*)out)[(size_t)n * 64 + lane] = r;
  }
}

extern "C" void kernel_launch(void* const* d_in, const int* in_sizes, int n_in,
                              void* d_out, int out_size, void* d_ws, size_t ws_size,
                              hipStream_t stream) {
  const float* x    = (const float*)d_in[0];
  const int*   ei   = (const int*)d_in[1];   // [2, E] int32
  const float* W1   = (const float*)d_in[2];
  const float* att1 = (const float*)d_in[3];
  const float* b1   = (const float*)d_in[4];
  const float* W2   = (const float*)d_in[5];
  const float* att2 = (const float*)d_in[6];
  const float* b2   = (const float*)d_in[7];
  float* out = (float*)d_out;

  const int N = in_sizes[0] / 128;   // 50000  (< 65536: u16 node ids OK)
  const int E = in_sizes[1] / 2;     // 800000
  const int* srcE = ei;
  const int* dstE = ei + E;

  // workspace layout (16B-sensitive arrays aligned)
  unsigned* hq = (unsigned*)d_ws;                 // N*64 packed bf16x2
  float* si    = (float*)(hq + (size_t)N * 64);   // N*2
  float* sj    = si + (size_t)N * 2;              // N*2
  float* Z     = sj + (size_t)N * 2;              // 4 (L1: Z[0..1], L2: Z[2..3])
  float* x2    = Z + 4;                           // N*64 f32 region
  unsigned short* partial = (unsigned short*)x2;  // HG*N u16 (dies pre-x2)
  unsigned short* x2b = (unsigned short*)x2;      // N*64 bf16 (after scatter)
  int* rowptr  = (int*)(x2 + (size_t)N * 64);     // N+1
  int* flags   = rowptr + (N + 1);                // 64 lookback flags
  uintptr_t ep = ((uintptr_t)(flags + 64) + 15) & ~(uintptr_t)15;
  uint2* erec  = (uint2*)ep;                      // E packed {s|d, bf16 w}
  unsigned short* wbf1 = (unsigned short*)(erec + E);  // 128*128 bf16 W1
  unsigned short* wbf2 = wbf1 + 128 * 128;             // 128*64 bf16 W2

  dim3 blk(256);
  dim3 blk1k(1024);
  int nb = (N + 1023) / 1024;      // 49 scan blocks (<= 64)
  int ntiles = (N + 63) / 64;
  int hstep = (N + HP - 1) / HP;   // 6250 <= HRANGE_MAX
  int eper  = (E + HG - 1) / HG;   // contiguous stripe width (12500)

  // 0) W -> bf16 + zero Z + flags=-1
  init_ws<<<64, blk, 0, stream>>>(W1, W2, wbf1, wbf2, Z, flags);
  // 1) hist (blocks[0,512), atomic-free, u16 flush) + gemm1 (MFMA, fp32 A)
  gemm_mfma<128, false><<<NHISTB + ntiles, blk, 0, stream>>>(
      x, wbf1, att1, hq, si, sj, N, dstE, partial, E, NHISTB, hstep, eper);
  // 2) single-pass merged scan (deltas in place + lookback rowptr)
  scan_full<<<nb, blk, 0, stream>>>(partial, rowptr, flags, N, E, nb);
  // 3) self-loop z1 + atomic-free scatter w/ 8B packed records + fused z1
  scatter_z<<<NSELF + NHISTB, blk1k, 0, stream>>>(
      srcE, dstE, partial, rowptr, erec, (const float2*)si,
      (const float2*)sj, Z, E, hstep, N, eper);
  // 4) layer-1 aggregation -> x2 (bf16 out; 8-deep pipelined; relu fused)
  csr_aggregate<<<4096, blk, 0, stream>>>(rowptr, erec, hq,
                                          (const float2*)si, (const float2*)sj,
                                          Z, b1, x2b, N, 1, 1);
  // 5) gemm2 (MFMA, bf16 A; nhistb=0: hist branch never taken)
  gemm_mfma<64, true><<<ntiles, blk, 0, stream>>>(
      x2b, wbf2, att2, hq, si, sj, N, dstE, partial, E, 0, hstep, eper);
  // 6) STREAMING layer-2 weight refresh + fused z2 (incl. self-loops)
  z_wgt2<<<NSELF + NWGT, blk1k, 0, stream>>>(
      (const float2*)si, (const float2*)sj, Z + 2, erec, E, N);
  // 7) layer-2 aggregation -> out (fp32)
  csr_aggregate<<<4096, blk, 0, stream>>>(rowptr, erec, hq,
                                          (const float2*)si, (const float2*)sj,
                                          Z + 2, b2, out, N, 0, 0);
}